// Round 1
// 399.833 us; speedup vs baseline: 1.1170x; 1.1170x over previous
//
#include <hip/hip_runtime.h>
#include <math.h>

#define GXD 128
#define GYD 128
#define GZD 128
#define VD 28
#define NRAYS 8192
#define NSAMP 128
#define NVOX (GXD * GYD * GZD)

// ---------- pass 1: fold the SH basis into the grid ----------
// einsum('rsck,k->rsc') commutes with trilinear interpolation (both linear),
// so per voxel precompute (sigma, r, g, b) = 4 floats. 28->4 features:
// grid footprint 235 MB fp32 -> 33.5 MB float4, all-fp32 (no quantization).
__global__ __launch_bounds__(256) void predot_grid(
    const float* __restrict__ g,
    const float* __restrict__ ang,
    float4* __restrict__ o)
{
    __shared__ float sb[9];
    if (threadIdx.x == 0) {
        float st, ct, sp, cp;
        sincosf(ang[0], &st, &ct);
        sincosf(ang[1], &sp, &cp);
        sb[0] = 0.28209479177387814f;
        sb[1] = 0.4886025119029199f * st * sp;
        sb[2] = 0.4886025119029199f * ct;
        sb[3] = 0.4886025119029199f * st * cp;
        sb[4] = 1.0925484305920792f * st * cp * st * sp;
        sb[5] = 1.0925484305920792f * st * sp * ct;
        sb[6] = 0.31539156525252005f * (3.0f * ct * ct - 1.0f);
        sb[7] = 1.0925484305920792f * st * cp * ct;
        sb[8] = 0.5462742152960396f * ((st * cp) * (st * cp) - (st * sp) * (st * sp));
    }
    __syncthreads();

    const int v = blockIdx.x * 256 + threadIdx.x;   // one voxel per thread
    const float4* __restrict__ p = (const float4*)(g + (size_t)v * VD); // 112B-aligned->16B ok
    float f[28];
    #pragma unroll
    for (int i = 0; i < 7; ++i)
        ((float4*)f)[i] = p[i];

    float r = 0.0f, gg = 0.0f, b = 0.0f;
    #pragma unroll
    for (int k = 0; k < 9; ++k) {
        r  += sb[k] * f[1 + k];
        gg += sb[k] * f[10 + k];
        b  += sb[k] * f[19 + k];
    }
    o[v] = make_float4(f[0], r, gg, b);
}

// ---------- pass 2: render from the pre-dotted float4 grid ----------
// One thread per sample: 8x float4 gathers (16 B each, z-pairs contiguous),
// 7 trilinear lerps on 4 components, att computed inline. 2 rays per
// 256-thread block; per-ray scan done by one wave (tid 0-63 / 128-191).
#define LERP4(a, b, t) make_float4( \
    fmaf((t), (b).x - (a).x, (a).x), \
    fmaf((t), (b).y - (a).y, (a).y), \
    fmaf((t), (b).z - (a).z, (a).z), \
    fmaf((t), (b).w - (a).w, (a).w))

__global__ __launch_bounds__(256) void render(
    const float4* __restrict__ vg,
    const float* __restrict__ pos,
    const float* __restrict__ dist,
    float* __restrict__ out)
{
    __shared__ float4 srgb[2][NSAMP];

    const int tid  = threadIdx.x;
    const int rloc = tid >> 7;          // 0/1: which of the block's 2 rays
    const int s    = tid & 127;
    const int ray  = blockIdx.x * 2 + rloc;
    const int sidx = ray * NSAMP + s;

    const float px = pos[sidx * 3 + 0];
    const float py = pos[sidx * 3 + 1];
    const float pz = pos[sidx * 3 + 2];
    const int ix = (int)floorf(px);
    const int iy = (int)floorf(py);
    const int iz = (int)floorf(pz);
    const float fx = px - (float)ix;
    const float fy = py - (float)iy;
    const float fz = pz - (float)iz;

    const float4* __restrict__ c = vg + (((size_t)ix * GYD + iy) * GZD + iz);
    const float4 c000 = c[0];
    const float4 c001 = c[1];
    const float4 c010 = c[GZD];
    const float4 c011 = c[GZD + 1];
    const float4 c100 = c[(size_t)GYD * GZD];
    const float4 c101 = c[(size_t)GYD * GZD + 1];
    const float4 c110 = c[(size_t)GYD * GZD + GZD];
    const float4 c111 = c[(size_t)GYD * GZD + GZD + 1];

    const float4 a00 = LERP4(c000, c001, fz);
    const float4 a01 = LERP4(c010, c011, fz);
    const float4 a10 = LERP4(c100, c101, fz);
    const float4 a11 = LERP4(c110, c111, fz);
    const float4 a0  = LERP4(a00, a01, fy);
    const float4 a1  = LERP4(a10, a11, fy);
    const float4 a   = LERP4(a0, a1, fx);

    const float d   = dist[sidx];
    const float att = expf(-a.x * d);
    srgb[rloc][s] = make_float4(att, a.y, a.z, a.w);
    __syncthreads();

    if ((tid & 127) < 64) {             // wave 0 handles ray0, wave 2 handles ray1
        const int lane = tid & 63;
        const float4 a0v = srgb[rloc][lane];
        const float4 a1v = srgb[rloc][lane + 64];
        const float att0 = a0v.x;
        const float att1 = a1v.x;

        float scan_lo = att0;
        #pragma unroll
        for (int off = 1; off < 64; off <<= 1) {
            const float v = __shfl_up(scan_lo, off, 64);
            if (lane >= off) scan_lo += v;
        }
        const float total_lo = __shfl(scan_lo, 63, 64);

        float scan_hi = att1;
        #pragma unroll
        for (int off = 1; off < 64; off <<= 1) {
            const float v = __shfl_up(scan_hi, off, 64);
            if (lane >= off) scan_hi += v;
        }
        const float w_lo = scan_lo * (1.0f - att0);
        const float w_hi = (total_lo + scan_hi) * (1.0f - att1);

        float o0 = w_lo * a0v.y + w_hi * a1v.y;
        float o1 = w_lo * a0v.z + w_hi * a1v.z;
        float o2 = w_lo * a0v.w + w_hi * a1v.w;

        #pragma unroll
        for (int off = 32; off > 0; off >>= 1) {
            o0 += __shfl_xor(o0, off, 64);
            o1 += __shfl_xor(o1, off, 64);
            o2 += __shfl_xor(o2, off, 64);
        }
        if (lane == 0) {
            out[ray * 3 + 0] = o0;
            out[ray * 3 + 1] = o1;
            out[ray * 3 + 2] = o2;
        }
    }
}

// ---------- fallback: proven fp32 kernel if ws too small ----------
__global__ __launch_bounds__(1024) void plenoxel_fused32(
    const float* __restrict__ grid,
    const float* __restrict__ pos,
    const float* __restrict__ dist,
    const float* __restrict__ ang,
    float* __restrict__ out)
{
    __shared__ float4 srgb[NSAMP];
    const int ray  = blockIdx.x;
    const int tid  = threadIdx.x;
    const int s    = tid >> 3;
    const int subl = tid & 7;
    const int dx   = (subl >> 2) & 1;
    const int dy   = (subl >> 1) & 1;
    const int zh   = subl & 1;

    const float theta = ang[0], phi = ang[1];
    float st, ct, sp, cp;
    sincosf(theta, &st, &ct);
    sincosf(phi,   &sp, &cp);
    float basis[9];
    basis[0] = 0.28209479177387814f;
    basis[1] = 0.4886025119029199f * st * sp;
    basis[2] = 0.4886025119029199f * ct;
    basis[3] = 0.4886025119029199f * st * cp;
    basis[4] = 1.0925484305920792f * st * cp * st * sp;
    basis[5] = 1.0925484305920792f * st * sp * ct;
    basis[6] = 0.31539156525252005f * (3.0f * ct * ct - 1.0f);
    basis[7] = 1.0925484305920792f * st * cp * ct;
    basis[8] = 0.5462742152960396f * ((st * cp) * (st * cp) - (st * sp) * (st * sp));

    const int sidx = ray * NSAMP + s;
    const float px = pos[sidx * 3 + 0];
    const float py = pos[sidx * 3 + 1];
    const float pz = pos[sidx * 3 + 2];
    const int ix = (int)floorf(px);
    const int iy = (int)floorf(py);
    const int iz = (int)floorf(pz);
    const float fx = px - (float)ix;
    const float fy = py - (float)iy;
    const float fz = pz - (float)iz;

    const float w = (dx ? fx : 1.0f - fx) *
                    (dy ? fy : 1.0f - fy) *
                    (zh ? fz : 1.0f - fz);

    const int base = (((ix + dx) * GYD + (iy + dy)) * GZD + (iz + zh)) * VD;
    const float4* __restrict__ q = (const float4*)(grid + base);
    float f[28];
    #pragma unroll
    for (int i = 0; i < 7; ++i)
        ((float4*)f)[i] = q[i];

    float psig = w * f[0];
    float pr = 0.0f, pg = 0.0f, pb = 0.0f;
    #pragma unroll
    for (int k = 0; k < 9; ++k) {
        pr += basis[k] * f[1 + k];
        pg += basis[k] * f[10 + k];
        pb += basis[k] * f[19 + k];
    }
    pr *= w; pg *= w; pb *= w;

    #pragma unroll
    for (int off = 1; off < 8; off <<= 1) {
        psig += __shfl_xor(psig, off, 64);
        pr   += __shfl_xor(pr,   off, 64);
        pg   += __shfl_xor(pg,   off, 64);
        pb   += __shfl_xor(pb,   off, 64);
    }
    if (subl == 0) srgb[s] = make_float4(psig, pr, pg, pb);
    __syncthreads();

    if (tid < 64) {
        const int lane = tid;
        const float4 a0 = srgb[lane];
        const float4 a1 = srgb[lane + 64];
        const float d0 = dist[ray * NSAMP + lane];
        const float d1 = dist[ray * NSAMP + lane + 64];
        const float att0 = expf(-a0.x * d0);
        const float att1 = expf(-a1.x * d1);

        float scan_lo = att0;
        #pragma unroll
        for (int off = 1; off < 64; off <<= 1) {
            const float v = __shfl_up(scan_lo, off, 64);
            if (lane >= off) scan_lo += v;
        }
        const float total_lo = __shfl(scan_lo, 63, 64);
        float scan_hi = att1;
        #pragma unroll
        for (int off = 1; off < 64; off <<= 1) {
            const float v = __shfl_up(scan_hi, off, 64);
            if (lane >= off) scan_hi += v;
        }
        const float w_lo = scan_lo * (1.0f - att0);
        const float w_hi = (total_lo + scan_hi) * (1.0f - att1);

        float o0 = w_lo * a0.y + w_hi * a1.y;
        float o1 = w_lo * a0.z + w_hi * a1.z;
        float o2 = w_lo * a0.w + w_hi * a1.w;
        #pragma unroll
        for (int off = 32; off > 0; off >>= 1) {
            o0 += __shfl_xor(o0, off, 64);
            o1 += __shfl_xor(o1, off, 64);
            o2 += __shfl_xor(o2, off, 64);
        }
        if (lane == 0) {
            out[ray * 3 + 0] = o0;
            out[ray * 3 + 1] = o1;
            out[ray * 3 + 2] = o2;
        }
    }
}

extern "C" void kernel_launch(void* const* d_in, const int* in_sizes, int n_in,
                              void* d_out, int out_size, void* d_ws, size_t ws_size,
                              hipStream_t stream) {
    const float* grid = (const float*)d_in[0];
    const float* pos  = (const float*)d_in[1];
    const float* dist = (const float*)d_in[2];
    const float* ang  = (const float*)d_in[3];
    float* out = (float*)d_out;

    const size_t need = (size_t)NVOX * sizeof(float4);   // 33.5 MB
    if (ws_size >= need) {
        float4* vg = (float4*)d_ws;
        predot_grid<<<NVOX / 256, 256, 0, stream>>>(grid, ang, vg);
        render<<<NRAYS / 2, 256, 0, stream>>>(vg, pos, dist, out);
    } else {
        plenoxel_fused32<<<NRAYS, 1024, 0, stream>>>(grid, pos, dist, ang, out);
    }
}

// Round 2
// 379.706 us; speedup vs baseline: 1.1762x; 1.0530x over previous
//
#include <hip/hip_runtime.h>
#include <hip/hip_fp16.h>
#include <math.h>

#define GXD 128
#define GYD 128
#define GZD 128
#define VD 28
#define NRAYS 8192
#define NSAMP 128
#define NVOX (GXD * GYD * GZD)

// ---------- pass 1: fold SH basis into grid, fp16 half4, quad layout ----------
// Per voxel precompute (sigma, r, g, b), store as 4x fp16 = 8 B.
// Quad layout: addr(uint2) = ((x>>1)*64 + (y>>1))*512 + z*4 + ((x&1)*2 + (y&1)).
// 2x2 (x,y) corners of a cell share a 32 B group; z-pairs 32 B apart ->
// expected ~2.8 cache lines per trilinear sample (vs 4.5 linear fp32).
// One block = one (xhi,yhi) super-column = 512 voxels = contiguous 4 KB output.
__global__ __launch_bounds__(256) void predot_quad(
    const float* __restrict__ g,
    const float* __restrict__ ang,
    uint2* __restrict__ o)
{
    __shared__ float sb[9];
    if (threadIdx.x == 0) {
        float st, ct, sp, cp;
        sincosf(ang[0], &st, &ct);
        sincosf(ang[1], &sp, &cp);
        sb[0] = 0.28209479177387814f;
        sb[1] = 0.4886025119029199f * st * sp;
        sb[2] = 0.4886025119029199f * ct;
        sb[3] = 0.4886025119029199f * st * cp;
        sb[4] = 1.0925484305920792f * st * cp * st * sp;
        sb[5] = 1.0925484305920792f * st * sp * ct;
        sb[6] = 0.31539156525252005f * (3.0f * ct * ct - 1.0f);
        sb[7] = 1.0925484305920792f * st * cp * ct;
        sb[8] = 0.5462742152960396f * ((st * cp) * (st * cp) - (st * sp) * (st * sp));
    }
    __syncthreads();

    const int xhi = blockIdx.x >> 6;
    const int yhi = blockIdx.x & 63;
    const int obase = blockIdx.x << 9;          // uint2 units: panel * 512

    #pragma unroll
    for (int q = 0; q < 2; ++q) {
        const int w   = q * 256 + threadIdx.x;  // 0..511 within super-column
        const int col = w >> 7;                 // 0..3 : (xlo<<1)|ylo
        const int z   = w & 127;
        const int x   = (xhi << 1) + (col >> 1);
        const int y   = (yhi << 1) + (col & 1);
        const size_t v = (((size_t)x << 7) | y) << 7 | z;

        const float4* __restrict__ p = (const float4*)(g + v * VD); // 112B-aligned
        float f[28];
        #pragma unroll
        for (int i = 0; i < 7; ++i)
            ((float4*)f)[i] = p[i];

        float r = 0.0f, gg = 0.0f, b = 0.0f;
        #pragma unroll
        for (int k = 0; k < 9; ++k) {
            r  += sb[k] * f[1 + k];
            gg += sb[k] * f[10 + k];
            b  += sb[k] * f[19 + k];
        }
        const __half2 h0 = __floats2half2_rn(f[0], r);
        const __half2 h1 = __floats2half2_rn(gg, b);
        uint2 u;
        u.x = *(const unsigned*)&h0;
        u.y = *(const unsigned*)&h1;
        o[obase + (z << 2) + col] = u;
    }
}

// ---------- pass 2: render from quad-layout fp16 grid ----------
#define LERP4(a, b, t) make_float4( \
    fmaf((t), (b).x - (a).x, (a).x), \
    fmaf((t), (b).y - (a).y, (a).y), \
    fmaf((t), (b).z - (a).z, (a).z), \
    fmaf((t), (b).w - (a).w, (a).w))

__device__ __forceinline__ float4 fetch_q(const uint2* __restrict__ vg,
                                          int x, int y, int z)
{
    const int p   = ((x >> 1) << 6) | (y >> 1);
    const int col = ((x & 1) << 1) | (y & 1);
    const uint2 u = vg[(p << 9) | (z << 2) | col];
    const float2 sr = __half22float2(*(const __half2*)&u.x);
    const float2 gb = __half22float2(*(const __half2*)&u.y);
    return make_float4(sr.x, sr.y, gb.x, gb.y);
}

__global__ __launch_bounds__(256) void render_q(
    const uint2* __restrict__ vg,
    const float* __restrict__ pos,
    const float* __restrict__ dist,
    float* __restrict__ out)
{
    __shared__ float4 srgb[2][NSAMP];

    const int tid  = threadIdx.x;
    const int rloc = tid >> 7;          // 0/1: which of the block's 2 rays
    const int s    = tid & 127;
    const int ray  = blockIdx.x * 2 + rloc;
    const int sidx = ray * NSAMP + s;

    const float px = pos[sidx * 3 + 0];
    const float py = pos[sidx * 3 + 1];
    const float pz = pos[sidx * 3 + 2];
    const int ix = (int)floorf(px);
    const int iy = (int)floorf(py);
    const int iz = (int)floorf(pz);
    const float fx = px - (float)ix;
    const float fy = py - (float)iy;
    const float fz = pz - (float)iz;

    const float4 c000 = fetch_q(vg, ix,     iy,     iz);
    const float4 c001 = fetch_q(vg, ix,     iy,     iz + 1);
    const float4 c010 = fetch_q(vg, ix,     iy + 1, iz);
    const float4 c011 = fetch_q(vg, ix,     iy + 1, iz + 1);
    const float4 c100 = fetch_q(vg, ix + 1, iy,     iz);
    const float4 c101 = fetch_q(vg, ix + 1, iy,     iz + 1);
    const float4 c110 = fetch_q(vg, ix + 1, iy + 1, iz);
    const float4 c111 = fetch_q(vg, ix + 1, iy + 1, iz + 1);

    const float4 a00 = LERP4(c000, c001, fz);
    const float4 a01 = LERP4(c010, c011, fz);
    const float4 a10 = LERP4(c100, c101, fz);
    const float4 a11 = LERP4(c110, c111, fz);
    const float4 a0  = LERP4(a00, a01, fy);
    const float4 a1  = LERP4(a10, a11, fy);
    const float4 a   = LERP4(a0, a1, fx);

    const float d   = dist[sidx];
    const float att = expf(-a.x * d);
    srgb[rloc][s] = make_float4(att, a.y, a.z, a.w);
    __syncthreads();

    if ((tid & 127) < 64) {             // wave 0 handles ray0, wave 2 handles ray1
        const int lane = tid & 63;
        const float4 a0v = srgb[rloc][lane];
        const float4 a1v = srgb[rloc][lane + 64];
        const float att0 = a0v.x;
        const float att1 = a1v.x;

        float scan_lo = att0;
        #pragma unroll
        for (int off = 1; off < 64; off <<= 1) {
            const float v = __shfl_up(scan_lo, off, 64);
            if (lane >= off) scan_lo += v;
        }
        const float total_lo = __shfl(scan_lo, 63, 64);

        float scan_hi = att1;
        #pragma unroll
        for (int off = 1; off < 64; off <<= 1) {
            const float v = __shfl_up(scan_hi, off, 64);
            if (lane >= off) scan_hi += v;
        }
        const float w_lo = scan_lo * (1.0f - att0);
        const float w_hi = (total_lo + scan_hi) * (1.0f - att1);

        float o0 = w_lo * a0v.y + w_hi * a1v.y;
        float o1 = w_lo * a0v.z + w_hi * a1v.z;
        float o2 = w_lo * a0v.w + w_hi * a1v.w;

        #pragma unroll
        for (int off = 32; off > 0; off >>= 1) {
            o0 += __shfl_xor(o0, off, 64);
            o1 += __shfl_xor(o1, off, 64);
            o2 += __shfl_xor(o2, off, 64);
        }
        if (lane == 0) {
            out[ray * 3 + 0] = o0;
            out[ray * 3 + 1] = o1;
            out[ray * 3 + 2] = o2;
        }
    }
}

// ---------- fallback: proven fp32 kernel if ws too small ----------
__global__ __launch_bounds__(1024) void plenoxel_fused32(
    const float* __restrict__ grid,
    const float* __restrict__ pos,
    const float* __restrict__ dist,
    const float* __restrict__ ang,
    float* __restrict__ out)
{
    __shared__ float4 srgb[NSAMP];
    const int ray  = blockIdx.x;
    const int tid  = threadIdx.x;
    const int s    = tid >> 3;
    const int subl = tid & 7;
    const int dx   = (subl >> 2) & 1;
    const int dy   = (subl >> 1) & 1;
    const int zh   = subl & 1;

    const float theta = ang[0], phi = ang[1];
    float st, ct, sp, cp;
    sincosf(theta, &st, &ct);
    sincosf(phi,   &sp, &cp);
    float basis[9];
    basis[0] = 0.28209479177387814f;
    basis[1] = 0.4886025119029199f * st * sp;
    basis[2] = 0.4886025119029199f * ct;
    basis[3] = 0.4886025119029199f * st * cp;
    basis[4] = 1.0925484305920792f * st * cp * st * sp;
    basis[5] = 1.0925484305920792f * st * sp * ct;
    basis[6] = 0.31539156525252005f * (3.0f * ct * ct - 1.0f);
    basis[7] = 1.0925484305920792f * st * cp * ct;
    basis[8] = 0.5462742152960396f * ((st * cp) * (st * cp) - (st * sp) * (st * sp));

    const int sidx = ray * NSAMP + s;
    const float px = pos[sidx * 3 + 0];
    const float py = pos[sidx * 3 + 1];
    const float pz = pos[sidx * 3 + 2];
    const int ix = (int)floorf(px);
    const int iy = (int)floorf(py);
    const int iz = (int)floorf(pz);
    const float fx = px - (float)ix;
    const float fy = py - (float)iy;
    const float fz = pz - (float)iz;

    const float w = (dx ? fx : 1.0f - fx) *
                    (dy ? fy : 1.0f - fy) *
                    (zh ? fz : 1.0f - fz);

    const int base = (((ix + dx) * GYD + (iy + dy)) * GZD + (iz + zh)) * VD;
    const float4* __restrict__ q = (const float4*)(grid + base);
    float f[28];
    #pragma unroll
    for (int i = 0; i < 7; ++i)
        ((float4*)f)[i] = q[i];

    float psig = w * f[0];
    float pr = 0.0f, pg = 0.0f, pb = 0.0f;
    #pragma unroll
    for (int k = 0; k < 9; ++k) {
        pr += basis[k] * f[1 + k];
        pg += basis[k] * f[10 + k];
        pb += basis[k] * f[19 + k];
    }
    pr *= w; pg *= w; pb *= w;

    #pragma unroll
    for (int off = 1; off < 8; off <<= 1) {
        psig += __shfl_xor(psig, off, 64);
        pr   += __shfl_xor(pr,   off, 64);
        pg   += __shfl_xor(pg,   off, 64);
        pb   += __shfl_xor(pb,   off, 64);
    }
    if (subl == 0) srgb[s] = make_float4(psig, pr, pg, pb);
    __syncthreads();

    if (tid < 64) {
        const int lane = tid;
        const float4 a0 = srgb[lane];
        const float4 a1 = srgb[lane + 64];
        const float d0 = dist[ray * NSAMP + lane];
        const float d1 = dist[ray * NSAMP + lane + 64];
        const float att0 = expf(-a0.x * d0);
        const float att1 = expf(-a1.x * d1);

        float scan_lo = att0;
        #pragma unroll
        for (int off = 1; off < 64; off <<= 1) {
            const float v = __shfl_up(scan_lo, off, 64);
            if (lane >= off) scan_lo += v;
        }
        const float total_lo = __shfl(scan_lo, 63, 64);
        float scan_hi = att1;
        #pragma unroll
        for (int off = 1; off < 64; off <<= 1) {
            const float v = __shfl_up(scan_hi, off, 64);
            if (lane >= off) scan_hi += v;
        }
        const float w_lo = scan_lo * (1.0f - att0);
        const float w_hi = (total_lo + scan_hi) * (1.0f - att1);

        float o0 = w_lo * a0.y + w_hi * a1.y;
        float o1 = w_lo * a0.z + w_hi * a1.z;
        float o2 = w_lo * a0.w + w_hi * a1.w;
        #pragma unroll
        for (int off = 32; off > 0; off >>= 1) {
            o0 += __shfl_xor(o0, off, 64);
            o1 += __shfl_xor(o1, off, 64);
            o2 += __shfl_xor(o2, off, 64);
        }
        if (lane == 0) {
            out[ray * 3 + 0] = o0;
            out[ray * 3 + 1] = o1;
            out[ray * 3 + 2] = o2;
        }
    }
}

extern "C" void kernel_launch(void* const* d_in, const int* in_sizes, int n_in,
                              void* d_out, int out_size, void* d_ws, size_t ws_size,
                              hipStream_t stream) {
    const float* grid = (const float*)d_in[0];
    const float* pos  = (const float*)d_in[1];
    const float* dist = (const float*)d_in[2];
    const float* ang  = (const float*)d_in[3];
    float* out = (float*)d_out;

    const size_t need = (size_t)NVOX * sizeof(uint2);   // 16.8 MB
    if (ws_size >= need) {
        uint2* vg = (uint2*)d_ws;
        predot_quad<<<4096, 256, 0, stream>>>(grid, ang, vg);
        render_q<<<NRAYS / 2, 256, 0, stream>>>(vg, pos, dist, out);
    } else {
        plenoxel_fused32<<<NRAYS, 1024, 0, stream>>>(grid, pos, dist, ang, out);
    }
}

// Round 3
// 368.216 us; speedup vs baseline: 1.2129x; 1.0312x over previous
//
#include <hip/hip_runtime.h>
#include <hip/hip_fp16.h>
#include <math.h>

#define GXD 128
#define GYD 128
#define GZD 128
#define VD 28
#define NRAYS 8192
#define NSAMP 128
#define NVOX (GXD * GYD * GZD)

// ---------- pass 1: fold SH basis into grid; z-duplicated fp16 layout ----------
// Entry(x,y,z) = { half4(voxel z), half4(voxel z+1) } = 16 B, so a trilinear
// sample needs only FOUR 16-B loads (one per (x,y) corner), each containing
// both z corners. Quad layout on (x,y):
//   byte addr = panel(x>>1,y>>1)*8192 + (z*4 + (x&1)*2 + (y&1))*16
// A 128-B line holds 8 entries (2 z's x 4 cols) -> lines/sample = panels only
// (expected 2.25, vs 2.81 for the non-duplicated quad layout).
// Each thread computes ONE voxel and stores it into its two entry slots:
// entry(z).lo and entry(z-1).hi  (two 8-B stores; the lo/hi stride-16 streams
// jointly cover full lines, so write-combining stays efficient).
__global__ __launch_bounds__(256) void predot_dupz(
    const float* __restrict__ g,
    const float* __restrict__ ang,
    char* __restrict__ o)
{
    __shared__ float sb[9];
    if (threadIdx.x == 0) {
        float st, ct, sp, cp;
        sincosf(ang[0], &st, &ct);
        sincosf(ang[1], &sp, &cp);
        sb[0] = 0.28209479177387814f;
        sb[1] = 0.4886025119029199f * st * sp;
        sb[2] = 0.4886025119029199f * ct;
        sb[3] = 0.4886025119029199f * st * cp;
        sb[4] = 1.0925484305920792f * st * cp * st * sp;
        sb[5] = 1.0925484305920792f * st * sp * ct;
        sb[6] = 0.31539156525252005f * (3.0f * ct * ct - 1.0f);
        sb[7] = 1.0925484305920792f * st * cp * ct;
        sb[8] = 0.5462742152960396f * ((st * cp) * (st * cp) - (st * sp) * (st * sp));
    }
    __syncthreads();

    const int xhi = blockIdx.x >> 6;
    const int yhi = blockIdx.x & 63;
    char* __restrict__ ob = o + (size_t)blockIdx.x * 8192;  // one 8 KB panel/block

    #pragma unroll
    for (int q = 0; q < 2; ++q) {
        const int w   = q * 256 + threadIdx.x;   // entry index within panel
        const int z   = w >> 2;
        const int col = w & 3;
        const int x   = (xhi << 1) + (col >> 1);
        const int y   = (yhi << 1) + (col & 1);
        const size_t v = ((((size_t)x << 7) | y) << 7) | z;

        const float4* __restrict__ p = (const float4*)(g + v * VD); // 112B-aligned
        float f[28];
        #pragma unroll
        for (int i = 0; i < 7; ++i)
            ((float4*)f)[i] = p[i];

        float r = 0.0f, gg = 0.0f, b = 0.0f;
        #pragma unroll
        for (int k = 0; k < 9; ++k) {
            r  += sb[k] * f[1 + k];
            gg += sb[k] * f[10 + k];
            b  += sb[k] * f[19 + k];
        }
        const __half2 h0 = __floats2half2_rn(f[0], r);
        const __half2 h1 = __floats2half2_rn(gg, b);
        uint2 u;
        u.x = *(const unsigned*)&h0;
        u.y = *(const unsigned*)&h1;

        *(uint2*)(ob + w * 16) = u;                    // entry(z).lo  = voxel z
        if (w >= 4)
            *(uint2*)(ob + (w - 4) * 16 + 8) = u;      // entry(z-1).hi = voxel z
        // entry(127).hi is never written; samples have iz <= 125, never read.
    }
}

// ---------- pass 2: render; 4x 16-B gathers, z-lerp folded into fetch ----------
#define LERP4(a, b, t) make_float4( \
    fmaf((t), (b).x - (a).x, (a).x), \
    fmaf((t), (b).y - (a).y, (a).y), \
    fmaf((t), (b).z - (a).z, (a).z), \
    fmaf((t), (b).w - (a).w, (a).w))

__device__ __forceinline__ float4 zlerp_fetch(const uint4* __restrict__ vg,
                                              int x, int y, int z, float fz)
{
    const int p   = ((x >> 1) << 6) | (y >> 1);
    const int col = ((x & 1) << 1) | (y & 1);
    const uint4 u = vg[(p << 9) | (z << 2) | col];
    const float2 aa = __half22float2(*(const __half2*)&u.x);  // voxel z   : sig,r
    const float2 ab = __half22float2(*(const __half2*)&u.y);  //            g,b
    const float2 ba = __half22float2(*(const __half2*)&u.z);  // voxel z+1 : sig,r
    const float2 bb = __half22float2(*(const __half2*)&u.w);  //            g,b
    return make_float4(fmaf(fz, ba.x - aa.x, aa.x),
                       fmaf(fz, ba.y - aa.y, aa.y),
                       fmaf(fz, bb.x - ab.x, ab.x),
                       fmaf(fz, bb.y - ab.y, ab.y));
}

__global__ __launch_bounds__(256) void render_d(
    const uint4* __restrict__ vg,
    const float* __restrict__ pos,
    const float* __restrict__ dist,
    float* __restrict__ out)
{
    __shared__ float4 srgb[2][NSAMP];

    const int tid  = threadIdx.x;
    const int rloc = tid >> 7;          // 0/1: which of the block's 2 rays
    const int s    = tid & 127;
    const int ray  = blockIdx.x * 2 + rloc;
    const int sidx = ray * NSAMP + s;

    const float px = pos[sidx * 3 + 0];
    const float py = pos[sidx * 3 + 1];
    const float pz = pos[sidx * 3 + 2];
    const int ix = (int)floorf(px);
    const int iy = (int)floorf(py);
    const int iz = (int)floorf(pz);
    const float fx = px - (float)ix;
    const float fy = py - (float)iy;
    const float fz = pz - (float)iz;

    const float4 a00 = zlerp_fetch(vg, ix,     iy,     iz, fz);
    const float4 a01 = zlerp_fetch(vg, ix,     iy + 1, iz, fz);
    const float4 a10 = zlerp_fetch(vg, ix + 1, iy,     iz, fz);
    const float4 a11 = zlerp_fetch(vg, ix + 1, iy + 1, iz, fz);

    const float4 a0 = LERP4(a00, a01, fy);
    const float4 a1 = LERP4(a10, a11, fy);
    const float4 a  = LERP4(a0, a1, fx);

    const float d   = dist[sidx];
    const float att = expf(-a.x * d);
    srgb[rloc][s] = make_float4(att, a.y, a.z, a.w);
    __syncthreads();

    if ((tid & 127) < 64) {             // wave 0 handles ray0, wave 2 handles ray1
        const int lane = tid & 63;
        const float4 a0v = srgb[rloc][lane];
        const float4 a1v = srgb[rloc][lane + 64];
        const float att0 = a0v.x;
        const float att1 = a1v.x;

        float scan_lo = att0;
        #pragma unroll
        for (int off = 1; off < 64; off <<= 1) {
            const float v = __shfl_up(scan_lo, off, 64);
            if (lane >= off) scan_lo += v;
        }
        const float total_lo = __shfl(scan_lo, 63, 64);

        float scan_hi = att1;
        #pragma unroll
        for (int off = 1; off < 64; off <<= 1) {
            const float v = __shfl_up(scan_hi, off, 64);
            if (lane >= off) scan_hi += v;
        }
        const float w_lo = scan_lo * (1.0f - att0);
        const float w_hi = (total_lo + scan_hi) * (1.0f - att1);

        float o0 = w_lo * a0v.y + w_hi * a1v.y;
        float o1 = w_lo * a0v.z + w_hi * a1v.z;
        float o2 = w_lo * a0v.w + w_hi * a1v.w;

        #pragma unroll
        for (int off = 32; off > 0; off >>= 1) {
            o0 += __shfl_xor(o0, off, 64);
            o1 += __shfl_xor(o1, off, 64);
            o2 += __shfl_xor(o2, off, 64);
        }
        if (lane == 0) {
            out[ray * 3 + 0] = o0;
            out[ray * 3 + 1] = o1;
            out[ray * 3 + 2] = o2;
        }
    }
}

// ---------- fallback: proven fp32 kernel if ws too small ----------
__global__ __launch_bounds__(1024) void plenoxel_fused32(
    const float* __restrict__ grid,
    const float* __restrict__ pos,
    const float* __restrict__ dist,
    const float* __restrict__ ang,
    float* __restrict__ out)
{
    __shared__ float4 srgb[NSAMP];
    const int ray  = blockIdx.x;
    const int tid  = threadIdx.x;
    const int s    = tid >> 3;
    const int subl = tid & 7;
    const int dx   = (subl >> 2) & 1;
    const int dy   = (subl >> 1) & 1;
    const int zh   = subl & 1;

    const float theta = ang[0], phi = ang[1];
    float st, ct, sp, cp;
    sincosf(theta, &st, &ct);
    sincosf(phi,   &sp, &cp);
    float basis[9];
    basis[0] = 0.28209479177387814f;
    basis[1] = 0.4886025119029199f * st * sp;
    basis[2] = 0.4886025119029199f * ct;
    basis[3] = 0.4886025119029199f * st * cp;
    basis[4] = 1.0925484305920792f * st * cp * st * sp;
    basis[5] = 1.0925484305920792f * st * sp * ct;
    basis[6] = 0.31539156525252005f * (3.0f * ct * ct - 1.0f);
    basis[7] = 1.0925484305920792f * st * cp * ct;
    basis[8] = 0.5462742152960396f * ((st * cp) * (st * cp) - (st * sp) * (st * sp));

    const int sidx = ray * NSAMP + s;
    const float px = pos[sidx * 3 + 0];
    const float py = pos[sidx * 3 + 1];
    const float pz = pos[sidx * 3 + 2];
    const int ix = (int)floorf(px);
    const int iy = (int)floorf(py);
    const int iz = (int)floorf(pz);
    const float fx = px - (float)ix;
    const float fy = py - (float)iy;
    const float fz = pz - (float)iz;

    const float w = (dx ? fx : 1.0f - fx) *
                    (dy ? fy : 1.0f - fy) *
                    (zh ? fz : 1.0f - fz);

    const int base = (((ix + dx) * GYD + (iy + dy)) * GZD + (iz + zh)) * VD;
    const float4* __restrict__ q = (const float4*)(grid + base);
    float f[28];
    #pragma unroll
    for (int i = 0; i < 7; ++i)
        ((float4*)f)[i] = q[i];

    float psig = w * f[0];
    float pr = 0.0f, pg = 0.0f, pb = 0.0f;
    #pragma unroll
    for (int k = 0; k < 9; ++k) {
        pr += basis[k] * f[1 + k];
        pg += basis[k] * f[10 + k];
        pb += basis[k] * f[19 + k];
    }
    pr *= w; pg *= w; pb *= w;

    #pragma unroll
    for (int off = 1; off < 8; off <<= 1) {
        psig += __shfl_xor(psig, off, 64);
        pr   += __shfl_xor(pr,   off, 64);
        pg   += __shfl_xor(pg,   off, 64);
        pb   += __shfl_xor(pb,   off, 64);
    }
    if (subl == 0) srgb[s] = make_float4(psig, pr, pg, pb);
    __syncthreads();

    if (tid < 64) {
        const int lane = tid;
        const float4 a0 = srgb[lane];
        const float4 a1 = srgb[lane + 64];
        const float d0 = dist[ray * NSAMP + lane];
        const float d1 = dist[ray * NSAMP + lane + 64];
        const float att0 = expf(-a0.x * d0);
        const float att1 = expf(-a1.x * d1);

        float scan_lo = att0;
        #pragma unroll
        for (int off = 1; off < 64; off <<= 1) {
            const float v = __shfl_up(scan_lo, off, 64);
            if (lane >= off) scan_lo += v;
        }
        const float total_lo = __shfl(scan_lo, 63, 64);
        float scan_hi = att1;
        #pragma unroll
        for (int off = 1; off < 64; off <<= 1) {
            const float v = __shfl_up(scan_hi, off, 64);
            if (lane >= off) scan_hi += v;
        }
        const float w_lo = scan_lo * (1.0f - att0);
        const float w_hi = (total_lo + scan_hi) * (1.0f - att1);

        float o0 = w_lo * a0.y + w_hi * a1.y;
        float o1 = w_lo * a0.z + w_hi * a1.z;
        float o2 = w_lo * a0.w + w_hi * a1.w;
        #pragma unroll
        for (int off = 32; off > 0; off >>= 1) {
            o0 += __shfl_xor(o0, off, 64);
            o1 += __shfl_xor(o1, off, 64);
            o2 += __shfl_xor(o2, off, 64);
        }
        if (lane == 0) {
            out[ray * 3 + 0] = o0;
            out[ray * 3 + 1] = o1;
            out[ray * 3 + 2] = o2;
        }
    }
}

extern "C" void kernel_launch(void* const* d_in, const int* in_sizes, int n_in,
                              void* d_out, int out_size, void* d_ws, size_t ws_size,
                              hipStream_t stream) {
    const float* grid = (const float*)d_in[0];
    const float* pos  = (const float*)d_in[1];
    const float* dist = (const float*)d_in[2];
    const float* ang  = (const float*)d_in[3];
    float* out = (float*)d_out;

    const size_t need = (size_t)NVOX * 16;   // 33.5 MB (z-duplicated entries)
    if (ws_size >= need) {
        predot_dupz<<<4096, 256, 0, stream>>>(grid, ang, (char*)d_ws);
        render_d<<<NRAYS / 2, 256, 0, stream>>>((const uint4*)d_ws, pos, dist, out);
    } else {
        plenoxel_fused32<<<NRAYS, 1024, 0, stream>>>(grid, pos, dist, ang, out);
    }
}